// Round 13
// baseline (209.971 us; speedup 1.0000x reference)
//
#include <hip/hip_runtime.h>
#include <hip/hip_bf16.h>

#define NCH 256      // C
#define NHD 8        // heads
#define HD 32        // head dim
#define NPIX 2304    // 48*48
#define H1DIM 512

typedef __attribute__((ext_vector_type(8))) __bf16 bf16x8;
typedef __attribute__((ext_vector_type(4))) float f32x4;

// ---------------- prep: x NCHW f32 -> NHWC bf16  +  weight cast --------------
__global__ __launch_bounds__(256) void prep_k(
    const float* __restrict__ x,
    const float* __restrict__ w0, const float* __restrict__ w1,
    const float* __restrict__ w2, const float* __restrict__ w3,
    const float* __restrict__ w4,
    __bf16* __restrict__ Xb, __bf16* __restrict__ Wall) {
    const int tid = threadIdx.x;
    if (blockIdx.x < 288) {
        const int t = blockIdx.x;
        const int b = t / 144, r0 = t % 144;
        const int c0 = (r0 / 36) * 64, n0 = (r0 % 36) * 64;
        __shared__ float tile[64][65];
        const size_t sb = ((size_t)b * NCH + c0) * NPIX + n0;
#pragma unroll
        for (int i = 0; i < 16; ++i) {
            int idx = tid + i * 256;
            int rr = idx >> 6, cc = idx & 63;
            tile[rr][cc] = x[sb + (size_t)rr * NPIX + cc];
        }
        __syncthreads();
#pragma unroll
        for (int i = 0; i < 8; ++i) {
            int idx = tid + i * 256;
            int nn = idx >> 5, cp = (idx & 31) * 2;
            union { __bf16 h[2]; unsigned u; } pk;
            pk.h[0] = (__bf16)tile[cp][nn];
            pk.h[1] = (__bf16)tile[cp + 1][nn];
            *(unsigned*)&Xb[((size_t)b * NPIX + n0 + nn) * NCH + c0 + cp] = pk.u;
        }
    } else {
        int i = (blockIdx.x - 288) * 256 + tid;   // float4 index over 131072
        const float* src; int off;
        if (i < 32768)      { src = w0; off = i; }
        else if (i < 49152) { src = w1; off = i - 32768; }
        else if (i < 65536) { src = w2; off = i - 49152; }
        else if (i < 98304) { src = w3; off = i - 65536; }
        else                { src = w4; off = i - 98304; }
        float4 v = ((const float4*)src)[off];
        union { __bf16 h[4]; uint2 u; } pk;
        pk.h[0] = (__bf16)v.x; pk.h[1] = (__bf16)v.y;
        pk.h[2] = (__bf16)v.z; pk.h[3] = (__bf16)v.w;
        ((uint2*)Wall)[i] = pk.u;
    }
}

// ---------------- fused qk+v conv: 32px x 16oc per wave ----------------------
// grid (72, 12, B), 4 waves; wave oc-tile = y*4+w in [0,48): 0-31 qk, 32-47 v.
// Block's 4 waves share the 32-px A-tile (L1 reuse).
__global__ __launch_bounds__(256) void qkv_k(
    const __bf16* __restrict__ A, const __bf16* __restrict__ Wq,
    const __bf16* __restrict__ Wv, const float* __restrict__ qk_b,
    const float* __restrict__ v_b, __bf16* __restrict__ Qb,
    __bf16* __restrict__ Kf, float* __restrict__ v_bu,
    __bf16* __restrict__ Vf) {
    const int tid = threadIdx.x;
    const int wave = tid >> 6, lane = tid & 63;
    const int l16 = lane & 15, quad = lane >> 4;
    const int m0 = blockIdx.x * 32;
    const int idx = blockIdx.y * 4 + wave;     // oc-tile in [0,48)
    const int b = blockIdx.z;
    const bool isv = idx >= 32;
    const int oc0 = (isv ? idx - 32 : idx) * 16;
    const __bf16* W = isv ? Wv : Wq;

    const __bf16* aptr = A + ((size_t)b * NPIX + m0 + l16) * NCH + quad * 8;
    const __bf16* bptr = W + (size_t)(oc0 + l16) * NCH + quad * 8;

    f32x4 acc0 = {0.f,0.f,0.f,0.f}, acc1 = {0.f,0.f,0.f,0.f};
#pragma unroll 8
    for (int k = 0; k < NCH; k += 32) {
        bf16x8 bf = *(const bf16x8*)(bptr + k);
        bf16x8 a0 = *(const bf16x8*)(aptr + k);
        bf16x8 a1 = *(const bf16x8*)(aptr + (size_t)16 * NCH + k);
        acc0 = __builtin_amdgcn_mfma_f32_16x16x32_bf16(a0, bf, acc0, 0, 0, 0);
        acc1 = __builtin_amdgcn_mfma_f32_16x16x32_bf16(a1, bf, acc1, 0, 0, 0);
    }

    const int oc = oc0 + l16;
#pragma unroll
    for (int mh = 0; mh < 2; ++mh) {
        const f32x4 acc = mh ? acc1 : acc0;
        const int m0h = m0 + mh * 16;
        const int mb = m0h + quad * 4;
        const int px16 = m0h >> 4;
        if (!isv) {
            const float bb = qk_b[oc];
            const int bh = b * NHD + (oc0 >> 6);
            const int dd = (oc0 & 16) + l16;
            if ((oc0 & 32) == 0) {
                const float qs = 0.17677669529663689f * 1.4426950408889634f;  // hd^-0.5 * log2e
#pragma unroll
                for (int r = 0; r < 4; ++r)
                    Qb[((size_t)bh * NPIX + mb + r) * 32 + dd] = (__bf16)((acc[r] + bb) * qs);
            } else {
                __bf16* kp = Kf + ((size_t)(bh * 144 + px16) * 64 + (dd >> 3) * 16 + quad * 4) * 8 + (dd & 7);
#pragma unroll
                for (int r = 0; r < 4; ++r) kp[r * 8] = (__bf16)(acc[r] + bb);
            }
        } else {
            const float bb = v_b[oc];
            const int bh = b * NHD + (oc0 >> 5);
            const int half = (oc0 >> 4) & 1;
            const size_t fb = ((size_t)b * NCH + oc) * NPIX + mb;
            float4 vf_; float* vp = &vf_.x;
            union { __bf16 hh[4]; uint2 u; } pk;
#pragma unroll
            for (int r = 0; r < 4; ++r) {
                float v = acc[r] + bb;
                vp[r] = v; pk.hh[r] = (__bf16)v;
            }
            *(float4*)&v_bu[fb] = vf_;
            *(uint2*)&Vf[((size_t)(bh * 144 + px16) * 64 + lane) * 8 + half * 4] = pk.u;
        }
    }
}

// ---------------- MFMA 1x1 conv: 32px x 16oc per wave ------------------------
// grid (72, OC/64, B), 4 waves = 4 consecutive oc-tiles sharing the A-tile.
// MODE 2: proj -> +resid(NCHW f32); out_f NCHW f32 (x1) + out_b NHWC bf16 (x1)
// MODE 3: fc1  -> silu; out_b NHWC bf16
// MODE 4: fc2  -> +resid(NCHW f32); out_f NCHW f32 (final)
template <int IC, int OC, int MODE>
__global__ __launch_bounds__(256) void convmm_k(
    const __bf16* __restrict__ A, const __bf16* __restrict__ W,
    const float* __restrict__ bias, const float* __restrict__ resid,
    float* __restrict__ out_f, __bf16* __restrict__ out_b) {
    const int tid = threadIdx.x;
    const int wave = tid >> 6, lane = tid & 63;
    const int l16 = lane & 15, quad = lane >> 4;
    const int m0 = blockIdx.x * 32;
    const int oc0 = (blockIdx.y * 4 + wave) * 16;
    const int b = blockIdx.z;

    const __bf16* aptr = A + ((size_t)b * NPIX + m0 + l16) * IC + quad * 8;
    const __bf16* bptr = W + (size_t)(oc0 + l16) * IC + quad * 8;

    f32x4 acc0 = {0.f,0.f,0.f,0.f}, acc1 = {0.f,0.f,0.f,0.f};
#pragma unroll 8
    for (int k = 0; k < IC; k += 32) {
        bf16x8 bf = *(const bf16x8*)(bptr + k);
        bf16x8 a0 = *(const bf16x8*)(aptr + k);
        bf16x8 a1 = *(const bf16x8*)(aptr + (size_t)16 * IC + k);
        acc0 = __builtin_amdgcn_mfma_f32_16x16x32_bf16(a0, bf, acc0, 0, 0, 0);
        acc1 = __builtin_amdgcn_mfma_f32_16x16x32_bf16(a1, bf, acc1, 0, 0, 0);
    }

    const int oc = oc0 + l16;
    const float bb = bias[oc];
#pragma unroll
    for (int mh = 0; mh < 2; ++mh) {
        const f32x4 acc = mh ? acc1 : acc0;
        const int mb = m0 + mh * 16 + quad * 4;
        if constexpr (MODE == 2) {
            const size_t fb = ((size_t)b * OC + oc) * NPIX + mb;
            float4 xr = *(const float4*)&resid[fb];
            const float* xp = &xr.x;
            float4 vf_; float* vp = &vf_.x;
#pragma unroll
            for (int r = 0; r < 4; ++r) {
                float v = acc[r] + bb + xp[r];
                vp[r] = v;
                out_b[((size_t)b * NPIX + mb + r) * OC + oc] = (__bf16)v;
            }
            *(float4*)&out_f[fb] = vf_;
        } else if constexpr (MODE == 3) {
#pragma unroll
            for (int r = 0; r < 4; ++r) {
                float v = acc[r] + bb;
                v = v / (1.f + __expf(-v));
                out_b[((size_t)b * NPIX + mb + r) * OC + oc] = (__bf16)v;
            }
        } else {  // MODE 4
            const size_t fb = ((size_t)b * OC + oc) * NPIX + mb;
            float4 xr = *(const float4*)&resid[fb];
            const float* xp = &xr.x;
            float4 vf_; float* vp = &vf_.x;
#pragma unroll
            for (int r = 0; r < 4; ++r) vp[r] = acc[r] + bb + xp[r];
            *(float4*)&out_f[fb] = vf_;
        }
    }
}

// ---------------- depthwise 7x7, SAME, per (b,c) plane ----------------
__global__ __launch_bounds__(256) void dwconv_k(const float* __restrict__ vb,
                                                const float* __restrict__ pw,
                                                const float* __restrict__ pb,
                                                float* __restrict__ pe) {
    const int c = blockIdx.x, b = blockIdx.y, tid = threadIdx.x;
    __shared__ float plane[NPIX];
    __shared__ float wk[49];
    const size_t base = ((size_t)b * NCH + c) * NPIX;
    for (int i = tid; i < NPIX; i += 256) plane[i] = vb[base + i];
    if (tid < 49) wk[tid] = pw[c * 49 + tid];
    float bb = pb[c];
    __syncthreads();
    for (int p = tid; p < NPIX; p += 256) {
        int y = p / 48, x = p - y * 48;
        float s = bb;
#pragma unroll
        for (int ky = 0; ky < 7; ++ky) {
            int yy = y + ky - 3;
            if ((unsigned)yy < 48u) {
#pragma unroll
                for (int kx = 0; kx < 7; ++kx) {
                    int xx = x + kx - 3;
                    if ((unsigned)xx < 48u) s += wk[ky * 7 + kx] * plane[yy * 48 + xx];
                }
            }
        }
        pe[base + p] = s;
    }
}

// ---------------- MFMA flash attention v7: 64q/wave, in-WG key-split 8 -------
// Block = 512 thr = 8 waves sharing 64 queries (4 Q-frags/wave); wave w walks
// tiles [w*18,(w+1)*18) -> each 2KB K/V tile feeds 12 MFMAs (traffic halved
// vs 32q). Partials via LDS; normalize + pe add -> NHWC bf16.
// grid (36, NH, B).
__global__ __launch_bounds__(512, 4) void attn7_k(const __bf16* __restrict__ Qb,
                                                  const __bf16* __restrict__ Kf,
                                                  const __bf16* __restrict__ Vf,
                                                  const float* __restrict__ pe,
                                                  __bf16* __restrict__ opb) {
    const int tid = threadIdx.x;
    const int wave = tid >> 6, lane = tid & 63;
    const int l16 = lane & 15, quad = lane >> 4;
    const int qb = blockIdx.x * 64;
    const int h = blockIdx.y, b = blockIdx.z;
    const int bh = b * NHD + h;

    __shared__ float o_s[8][32][65];   // [wave][d][q]
    __shared__ float l_s[8][64];       // [wave][q]

    bf16x8 b_q[4];
#pragma unroll
    for (int g = 0; g < 4; ++g)
        b_q[g] = *(const bf16x8*)(Qb + ((size_t)bh * NPIX + qb + g * 16 + l16) * 32 + quad * 8);

    const __bf16* kf = Kf + ((size_t)(bh * 144 + wave * 18) * 64 + lane) * 8;
    const __bf16* vf = Vf + ((size_t)(bh * 144 + wave * 18) * 64 + lane) * 8;

    f32x4 oacc[4][2];
    f32x4 lacc[4];
#pragma unroll
    for (int g = 0; g < 4; ++g) {
        oacc[g][0] = {0.f,0.f,0.f,0.f};
        oacc[g][1] = {0.f,0.f,0.f,0.f};
        lacc[g] = {0.f,0.f,0.f,0.f};
    }

#pragma unroll 2
    for (int t = 0; t < 18; ++t) {
        bf16x8 a_k = *(const bf16x8*)(kf + (size_t)t * 512);
        bf16x8 va  = *(const bf16x8*)(vf + (size_t)t * 512);
#pragma unroll
        for (int g = 0; g < 4; ++g) {
            f32x4 z = {0.f, 0.f, 0.f, 0.f};
            f32x4 s = __builtin_amdgcn_mfma_f32_16x16x32_bf16(a_k, b_q[g], z, 0, 0, 0);
            f32x4 p;
#pragma unroll
            for (int r = 0; r < 4; ++r) p[r] = __builtin_amdgcn_exp2f(s[r]);
            lacc[g] += p;
            bf16x8 blo = {}, bhi = {};
#pragma unroll
            for (int r = 0; r < 4; ++r) {
                __bf16 c = (__bf16)p[r];
                blo[r] = c; bhi[4 + r] = c;
            }
            oacc[g][0] = __builtin_amdgcn_mfma_f32_16x16x32_bf16(va, blo, oacc[g][0], 0, 0, 0);
            oacc[g][1] = __builtin_amdgcn_mfma_f32_16x16x32_bf16(va, bhi, oacc[g][1], 0, 0, 0);
        }
    }

#pragma unroll
    for (int g = 0; g < 4; ++g) {
        float ls = lacc[g][0] + lacc[g][1] + lacc[g][2] + lacc[g][3];
        ls += __shfl_xor(ls, 16); ls += __shfl_xor(ls, 32);
        if (quad == 0) l_s[wave][g * 16 + l16] = ls;
#pragma unroll
        for (int half = 0; half < 2; ++half)
#pragma unroll
            for (int r = 0; r < 4; ++r)
                o_s[wave][half * 16 + quad * 4 + r][g * 16 + l16] = oacc[g][half][r];
    }
    __syncthreads();

    // epilogue: wave w' -> channels d0..d0+3, q = lane (coalesced pe rows)
    const int q = lane;
    const int d0 = wave * 4;
    float l = 0.f;
#pragma unroll
    for (int w = 0; w < 8; ++w) l += l_s[w][q];
    const float inv = 1.f / l;
    const int n = qb + q;
    union { __bf16 hh[4]; uint2 u; } pk;
#pragma unroll
    for (int j = 0; j < 4; ++j) {
        float v = 0.f;
#pragma unroll
        for (int w = 0; w < 8; ++w) v += o_s[w][d0 + j][q];
        v = v * inv + pe[((size_t)b * NCH + h * HD + d0 + j) * NPIX + n];
        pk.hh[j] = (__bf16)v;
    }
    *(uint2*)&opb[((size_t)b * NPIX + n) * NCH + h * HD + d0] = pk.u;
}

extern "C" void kernel_launch(void* const* d_in, const int* in_sizes, int n_in,
                              void* d_out, int out_size, void* d_ws, size_t ws_size,
                              hipStream_t stream) {
    const float* x    = (const float*)d_in[0];
    const float* qk_w = (const float*)d_in[1];
    const float* qk_b = (const float*)d_in[2];
    const float* v_w  = (const float*)d_in[3];
    const float* v_b  = (const float*)d_in[4];
    const float* pe_w = (const float*)d_in[5];
    const float* pe_b = (const float*)d_in[6];
    const float* pj_w = (const float*)d_in[7];
    const float* pj_b = (const float*)d_in[8];
    const float* f1_w = (const float*)d_in[9];
    const float* f1_b = (const float*)d_in[10];
    const float* f2_w = (const float*)d_in[11];
    const float* f2_b = (const float*)d_in[12];
    float* out = (float*)d_out;

    const int B = 2;
    const size_t plane = (size_t)NCH * NPIX;       // 589824
    const size_t bp = (size_t)B * plane;           // 1179648

    float* v_bu  = (float*)d_ws;                   // NCHW f32
    float* pe_bu = v_bu + bp;
    float* x1_f  = pe_bu + bp;
    __bf16* Xb   = (__bf16*)(x1_f + bp);           // NHWC bf16 [b][n][256]
    __bf16* opb  = Xb + bp;                        // NHWC bf16 (attn+pe)
    __bf16* x1b  = opb + bp;                       // NHWC bf16
    __bf16* hb   = x1b + bp;                       // NHWC bf16 [b][n][512]
    __bf16* Qb   = hb + 2 * bp;                    // [bh][n][32] (pre-scaled)
    __bf16* Kf   = Qb + bp;                        // QK A-frag tiles
    __bf16* Vf   = Kf + bp;                        // PV A-frag tiles
    __bf16* Wall = Vf + bp;                        // 524288 bf16
    __bf16* Wq = Wall;
    __bf16* Wv = Wall + 131072;
    __bf16* Wp = Wall + 196608;
    __bf16* W1 = Wall + 262144;
    __bf16* W2 = Wall + 393216;

    // 1) x transpose + all weight casts
    prep_k<<<800, 256, 0, stream>>>(x, qk_w, v_w, pj_w, f1_w, f2_w, Xb, Wall);
    // 2) qk conv (-> Qb, Kf) + v conv (-> v_bu f32, Vf); 32x16 waves
    qkv_k<<<dim3(72, 12, B), 256, 0, stream>>>(Xb, Wq, Wv, qk_b, v_b, Qb, Kf, v_bu, Vf);
    // 3) pe = dwconv7x7(v_full) + pe_b
    dwconv_k<<<dim3(NCH, B), 256, 0, stream>>>(v_bu, pe_w, pe_b, pe_bu);
    // 4) attention: 64q/block, split 8; normalize + pe -> opb NHWC bf16
    attn7_k<<<dim3(36, NHD, B), 512, 0, stream>>>(Qb, Kf, Vf, pe_bu, opb);
    // 5) x1 = x + proj(o+pe): NCHW f32 + NHWC bf16
    convmm_k<256, 256, 2><<<dim3(72, 4, B), 256, 0, stream>>>(opb, Wp, pj_b, x, x1_f, x1b);
    // 6) h = silu(fc1(x1)) -> NHWC bf16
    convmm_k<256, 512, 3><<<dim3(72, 8, B), 256, 0, stream>>>(x1b, W1, f1_b, nullptr, nullptr, hb);
    // 7) out = x1 + fc2(h) -> NCHW f32
    convmm_k<512, 256, 4><<<dim3(72, 4, B), 256, 0, stream>>>(hb, W2, f2_b, x1_f, out, nullptr);
}